// Round 3
// baseline (8851.431 us; speedup 1.0000x reference)
//
#include <hip/hip_runtime.h>
#include <cstdint>
#include <cstddef>

typedef float    float4v __attribute__((ext_vector_type(4)));
typedef _Float16 f16x2   __attribute__((ext_vector_type(2)));
typedef _Float16 f16x8   __attribute__((ext_vector_type(8)));

#define DI __device__ __forceinline__

static const int Bsz = 64, Tlen = 2048, Hd = 128, G4 = 512;  // 4H=512
static const int Mrows = Bsz * Tlen;                          // 131072
static const int NB = 4;                                      // batches per rec WG
static const int HSTR = 136;                                  // padded H row (f16)
static const int GSTR = 520;                                  // padded G row (f32)

DI float sigf_fast(float x) {
    float e = __builtin_amdgcn_exp2f(-1.442695041f * x);
    return __builtin_amdgcn_rcpf(1.f + e);
}
DI float tanhf_fast(float x) {
    float e = __builtin_amdgcn_exp2f(-2.885390082f * x);
    return 2.f * __builtin_amdgcn_rcpf(1.f + e) - 1.f;
}

// load 8 consecutive f32, convert to f16x8
DI f16x8 cvt8(const float* p) {
    float4v u = *(const float4v*)p;
    float4v w = *(const float4v*)(p + 4);
    f16x8 o;
    o[0] = (_Float16)u[0]; o[1] = (_Float16)u[1]; o[2] = (_Float16)u[2]; o[3] = (_Float16)u[3];
    o[4] = (_Float16)w[0]; o[5] = (_Float16)w[1]; o[6] = (_Float16)w[2]; o[7] = (_Float16)w[3];
    return o;
}

// ---------------------------------------------------------------------------
// GEMM: C[M,N] = A[M,128] @ W[N,128]^T (+bias). f32 (or f16) A, f32 W,
// f16-convert fragments, MFMA f32_16x16x32_f16, f32 accumulate.
// Tile: 64(M) x 64(N) per WG of 256 threads. (verified correct in R2)
// ---------------------------------------------------------------------------
template <bool A_F16, bool OUT_F32>
__global__ __launch_bounds__(256) void gemm_k128(
    const void* __restrict__ Av, const float* __restrict__ W,
    const float* __restrict__ bias, void* __restrict__ Cout, int M, int N)
{
    const int lane = threadIdx.x & 63, wave = threadIdx.x >> 6;
    const int m0 = blockIdx.x * 64 + wave * 16;
    const int n0 = blockIdx.y * 64;
    const int r15 = lane & 15, kg = lane >> 4;   // kg in 0..3

    f16x8 a[4];
    if (A_F16) {
        const f16x8* Ar = (const f16x8*)((const _Float16*)Av + (size_t)(m0 + r15) * 128);
#pragma unroll
        for (int kt = 0; kt < 4; kt++) a[kt] = Ar[kt * 4 + kg];
    } else {
        const float* Ar = (const float*)Av + (size_t)(m0 + r15) * 128;
#pragma unroll
        for (int kt = 0; kt < 4; kt++) a[kt] = cvt8(Ar + kt * 32 + kg * 8);
    }

    f16x8 bfrg[4][4];
#pragma unroll
    for (int nt = 0; nt < 4; nt++) {
        const float* Wr = W + (size_t)(n0 + nt * 16 + r15) * 128;
#pragma unroll
        for (int kt = 0; kt < 4; kt++) bfrg[nt][kt] = cvt8(Wr + kt * 32 + kg * 8);
    }

    float4v acc[4] = {};
#pragma unroll
    for (int kt = 0; kt < 4; kt++)
#pragma unroll
        for (int nt = 0; nt < 4; nt++)
            acc[nt] = __builtin_amdgcn_mfma_f32_16x16x32_f16(a[kt], bfrg[nt][kt], acc[nt], 0, 0, 0);

#pragma unroll
    for (int nt = 0; nt < 4; nt++) {
        int n = n0 + nt * 16 + r15;
        float bv = bias ? bias[n] : 0.f;
#pragma unroll
        for (int r = 0; r < 4; r++) {
            int m = m0 + kg * 4 + r;
            float v = acc[nt][r] + bv;
            if (OUT_F32) ((float*)Cout)[(size_t)m * N + n] = v;
            else         ((_Float16*)Cout)[(size_t)m * N + n] = (_Float16)v;
        }
    }
}

// ---------------------------------------------------------------------------
// LSTM recurrence via MFMA. 16 WGs x 512 threads; 4 batch elements per WG.
// gates[512,16] = Whh[512,128] @ H^T[128,16] with mfma_f32_16x16x32_f16.
// Whh A-frags STATIC in VGPRs (16 frags/lane, loaded once). h read as
// distributed B-frags: 4 ds_read_b128/lane/step (vs 16 broadcast reads in R2).
// Wave w owns m-tiles {q*128+16w} for q=i,f,g,o -> stores raw gates to LDS
// (pad 520: conflict-free) -> 512 threads each do ONE (b,j) gate-set:
// 10 transcendentals, c in regs -> h to ping-pong H LDS (pad 136: 2-way=free).
// 2 barriers/step. XP (f16, bias-free) prefetched 1 step ahead.
// ---------------------------------------------------------------------------
template <bool HAS_XP, bool WRITE_Y, bool INIT>
__global__ __launch_bounds__(512) void lstm_rec_mfma(
    const float* __restrict__ U,                     // Whh [512,128] f32
    const float* __restrict__ bi, const float* __restrict__ bh,
    const _Float16* __restrict__ XP,                 // [B,T,512] f16 or null
    const float* __restrict__ ih, const float* __restrict__ ic,  // [B,128] or null
    _Float16* __restrict__ Yout,                     // [B,T,128] f16 or null
    float* __restrict__ fh, float* __restrict__ fc, int T)
{
    const int tid  = threadIdx.x;
    const int lane = tid & 63, wv = tid >> 6;        // 8 waves
    const int r15  = lane & 15, quad = lane >> 4;
    const int j0   = wv * 16;                        // this wave's j-range base
    const int b    = tid >> 7;                       // 0..3 (update-phase role)
    const int j    = tid & 127;
    const int bbase = blockIdx.x * NB;

    __shared__ alignas(16) _Float16 Hl[2 * 16 * HSTR];   // ping-pong h
    __shared__ alignas(16) float    Gl[NB * GSTR];       // raw gates

    // --- static A-fragments: Whh rows q*128 + j0 + r15, k = kc*32+quad*8+.. ---
    f16x8 af[4][4];
#pragma unroll
    for (int q = 0; q < 4; q++)
#pragma unroll
        for (int kc = 0; kc < 4; kc++)
            af[q][kc] = cvt8(U + (size_t)(q * 128 + j0 + r15) * 128 + kc * 32 + quad * 8);

    // --- per-(b,j) bias (update role) ---
    float bq[4];
#pragma unroll
    for (int q = 0; q < 4; q++) bq[q] = bi[q * 128 + j] + bh[q * 128 + j];

    // --- zero H buffers (garbage cols b>=4 are computed-but-unused; keep finite) ---
    for (int i = tid; i < 2 * 16 * HSTR; i += 512) Hl[i] = (_Float16)0.f;
    __syncthreads();

    // --- initial state ---
    float c, hv;
    if (INIT) {
        c  = ic[(size_t)(bbase + b) * 128 + j];
        hv = ih[(size_t)(bbase + b) * 128 + j];
    } else { c = 0.f; hv = 0.f; }
    Hl[b * HSTR + j] = (_Float16)hv;                 // buffer 0 = cur at t=0
    __syncthreads();

    // --- xp prefetch for t=0 ---
    _Float16 xpc[4] = {};
    if (HAS_XP) {
        const _Float16* xr = XP + ((size_t)(bbase + b) * T) * 512 + j;
#pragma unroll
        for (int q = 0; q < 4; q++) xpc[q] = xr[q * 128];
    }

    int cur = 0;
    for (int t = 0; t < T; t++) {
        // prefetch xp for t+1 (consumed next iteration)
        _Float16 xpn[4] = {};
        if (HAS_XP && (t + 1 < T)) {
            const _Float16* xr = XP + ((size_t)(bbase + b) * T + (t + 1)) * 512 + j;
#pragma unroll
            for (int q = 0; q < 4; q++) xpn[q] = xr[q * 128];
        }

        // ---- MFMA phase: gates = Whh @ H^T ----
        const _Float16* Hc = Hl + cur * (16 * HSTR);
        f16x8 bf[4];
#pragma unroll
        for (int kc = 0; kc < 4; kc++)
            bf[kc] = *(const f16x8*)(Hc + r15 * HSTR + kc * 32 + quad * 8);

        float4v acc[4] = {};
#pragma unroll
        for (int kc = 0; kc < 4; kc++)
#pragma unroll
            for (int q = 0; q < 4; q++)
                acc[q] = __builtin_amdgcn_mfma_f32_16x16x32_f16(af[q][kc], bf[kc], acc[q], 0, 0, 0);

        if (r15 < NB) {
#pragma unroll
            for (int q = 0; q < 4; q++)
                *(float4v*)(Gl + r15 * GSTR + q * 128 + j0 + quad * 4) = acc[q];
        }
        __syncthreads();

        // ---- update phase: one (b,j) gate-set per thread ----
        float g0 = Gl[b * GSTR +       j] + bq[0];
        float g1 = Gl[b * GSTR + 128 + j] + bq[1];
        float g2 = Gl[b * GSTR + 256 + j] + bq[2];
        float g3 = Gl[b * GSTR + 384 + j] + bq[3];
        if (HAS_XP) {
            g0 += (float)xpc[0]; g1 += (float)xpc[1];
            g2 += (float)xpc[2]; g3 += (float)xpc[3];
        }
        float iv = sigf_fast(g0), fv = sigf_fast(g1);
        float gv = tanhf_fast(g2), ov = sigf_fast(g3);
        c  = fv * c + iv * gv;
        hv = ov * tanhf_fast(c);
        Hl[(cur ^ 1) * (16 * HSTR) + b * HSTR + j] = (_Float16)hv;
        if (WRITE_Y)
            Yout[((size_t)(bbase + b) * T + t) * 128 + j] = (_Float16)hv;
        __syncthreads();

#pragma unroll
        for (int q = 0; q < 4; q++) xpc[q] = xpn[q];
        cur ^= 1;
    }

    fh[(size_t)(bbase + b) * 128 + j] = hv;
    fc[(size_t)(bbase + b) * 128 + j] = c;
}

// ---------------------------------------------------------------------------
// Host side: 8 stream-ordered launches.
//   ws: XP f16 [131072,512] (128MB) | Y f16 [131072,128] (32MB) | finals f32
// ---------------------------------------------------------------------------
extern "C" void kernel_launch(void* const* d_in, const int* in_sizes, int n_in,
                              void* d_out, int out_size, void* d_ws, size_t ws_size,
                              hipStream_t stream)
{
    const float* x    = (const float*)d_in[0];
    const float* eW0  = (const float*)d_in[1];
    const float* eU0  = (const float*)d_in[2];
    const float* eb0i = (const float*)d_in[3];
    const float* eb0h = (const float*)d_in[4];
    const float* eW1  = (const float*)d_in[5];
    const float* eU1  = (const float*)d_in[6];
    const float* eb1i = (const float*)d_in[7];
    const float* eb1h = (const float*)d_in[8];
    const float* dU0  = (const float*)d_in[10];
    const float* db0i = (const float*)d_in[11];
    const float* db0h = (const float*)d_in[12];
    const float* dW1  = (const float*)d_in[13];
    const float* dU1  = (const float*)d_in[14];
    const float* db1i = (const float*)d_in[15];
    const float* db1h = (const float*)d_in[16];
    const float* oW   = (const float*)d_in[17];
    const float* ob   = (const float*)d_in[18];

    char* ws = (char*)d_ws;
    _Float16* XP = (_Float16*)ws;                               // 134217728 B
    _Float16* Y  = (_Float16*)(ws + 134217728);                 //  33554432 B
    float*    fh0 = (float*)(ws + 167772160);
    float*    fc0 = fh0 + Bsz * Hd;
    float*    fh1 = fc0 + Bsz * Hd;
    float*    fc1 = fh1 + Bsz * Hd;

    dim3 blk(256);
    dim3 g512(Mrows / 64, G4 / 64);   // 2048 x 8
    dim3 g128(Mrows / 64, Hd / 64);   // 2048 x 2
    dim3 rgrid(Bsz / NB);             // 16
    dim3 rblk(512);

    // 1) XP = x @ enc_Wih0^T
    gemm_k128<false, false><<<g512, blk, 0, stream>>>((const void*)x, eW0, (const float*)nullptr, (void*)XP, Mrows, G4);
    // 2) enc L0
    lstm_rec_mfma<true, true, false><<<rgrid, rblk, 0, stream>>>(
        eU0, eb0i, eb0h, XP, (const float*)nullptr, (const float*)nullptr, Y, fh0, fc0, Tlen);
    // 3) XP = y0 @ enc_Wih1^T
    gemm_k128<true, false><<<g512, blk, 0, stream>>>((const void*)Y, eW1, (const float*)nullptr, (void*)XP, Mrows, G4);
    // 4) enc L1 (y discarded)
    lstm_rec_mfma<true, false, false><<<rgrid, rblk, 0, stream>>>(
        eU1, eb1i, eb1h, XP, (const float*)nullptr, (const float*)nullptr, (_Float16*)nullptr, fh1, fc1, Tlen);
    // 5) dec L0: zeros input, init (fh0,fc0)
    lstm_rec_mfma<false, true, true><<<rgrid, rblk, 0, stream>>>(
        dU0, db0i, db0h, (const _Float16*)nullptr, fh0, fc0, Y, fh0, fc0, Tlen);
    // 6) XP = d0 @ dec_Wih1^T
    gemm_k128<true, false><<<g512, blk, 0, stream>>>((const void*)Y, dW1, (const float*)nullptr, (void*)XP, Mrows, G4);
    // 7) dec L1: init (fh1,fc1)
    lstm_rec_mfma<true, true, true><<<rgrid, rblk, 0, stream>>>(
        dU1, db1i, db1h, XP, fh1, fc1, Y, fh1, fc1, Tlen);
    // 8) out = d1 @ out_W^T + out_b  (f32 -> d_out)
    gemm_k128<true, true><<<g128, blk, 0, stream>>>((const void*)Y, oW, ob, d_out, Mrows, Hd);
}